// Round 1
// 285.329 us; speedup vs baseline: 1.0948x; 1.0948x over previous
//
#include <hip/hip_runtime.h>

#define D 128
#define BSHIFT 7          // 128 nodes per bucket
#define NSUB 8            // sub-buckets per bucket, keyed by blockIdx&7 (XCD)
#define SUBCAP 384        // per-sub-bucket capacity: lambda=256, +8 sigma
#define CAP 2560          // whole-bucket LDS staging: lambda=2048, +11 sigma
#define LDSPITCH 136      // ushorts/row: 128+8 pad (2-way bank alias = free)

// bin_kernel LDS chunk staging
#define NBMAX 784         // >= nbuck (782), padded
#define LCAP 16           // ints staged per bucket in LDS
#define FCH 8             // flush granularity: 8 ints = 32 B = one L2 sector

typedef __attribute__((ext_vector_type(8))) short bf16x8;   // 8 bf16 = 4 VGPR
typedef __attribute__((ext_vector_type(4))) float f32x4;    // MFMA acc

__device__ __forceinline__ unsigned short f2bf(float f) {   // fp32 -> bf16 RNE
    union { float f; unsigned int u; } c; c.f = f;
    return (unsigned short)((c.u + 0x7FFFu + ((c.u >> 16) & 1u)) >> 16);
}

// ---------------------------------------------------------------------------
// x (fp32) -> xb (bf16) for the gather.
// ---------------------------------------------------------------------------
__global__ __launch_bounds__(256) void convert_kernel(
    const float* __restrict__ x, unsigned short* __restrict__ xb, int total4)
{
    int gid = blockIdx.x * 256 + threadIdx.x;
    if (gid >= total4) return;
    float4 v = ((const float4*)x)[gid];
    ushort4 o;
    o.x = f2bf(v.x); o.y = f2bf(v.y); o.z = f2bf(v.z); o.w = f2bf(v.w);
    ((ushort4*)xb)[gid] = o;
}

// ---------------------------------------------------------------------------
// W [k][n] fp32 -> Wt [n][k] bf16.
// ---------------------------------------------------------------------------
__global__ __launch_bounds__(256) void convw_kernel(
    const float* __restrict__ W, unsigned short* __restrict__ Wt)
{
    int gid = blockIdx.x * 256 + threadIdx.x;   // 0..16383
    int n = gid >> 7, k = gid & 127;
    Wt[n * 128 + k] = f2bf(W[k * 128 + n]);
}

// ---------------------------------------------------------------------------
// Bucket binning, round-10: LDS chunk aggregation.
// Round-9 measured 58 MB HBM writes for a 6.4 MB payload (9x amplification):
// 1.6M scattered 4 B writes each evict a 32 B L2 sector before it fills
// (frontier lines fill too slowly vs the 12.8 MB read stream's eviction
// pressure).  Fix: stage edges per-bucket in LDS (lbuf[784][16]) and flush
// aligned 8-int (32 B = one sector) chunks, so the HBM write stream is
// sector-granular.  Global cur atomics drop 1.6M -> ~250K and stay on the
// per-slice counters (slice = blockIdx&7 ~ XCD), preserving the round-9
// L2-local atomic property.  128 blocks so E/(blocks*nbuck) = 16 edges per
// LDS cell: ~75% of edges leave via aligned full-chunk flushes, ~25% drain
// at ~16 B granularity (<=2x amp).  Expected writes ~10 MB.
// Packs (dlocal<<17 | src); needs src < 2^17 (N=100000 ok).
// ---------------------------------------------------------------------------
__global__ __launch_bounds__(512) void bin_kernel(
    const int* __restrict__ ei, int* __restrict__ cur,
    int* __restrict__ pairs, int E, int nbuck)
{
    __shared__ int lbuf[NBMAX * LCAP];   // 50 KB
    __shared__ int lcnt[NBMAX];          // 3 KB

    int tid = threadIdx.x;
    int slice = blockIdx.x & (NSUB - 1);
    int nblocks = gridDim.x;
    int epb = (E + nblocks - 1) / nblocks;
    int start = blockIdx.x * epb;
    int end = min(start + epb, E);

    for (int b = tid; b < nbuck; b += 512) lcnt[b] = 0;
    __syncthreads();

    for (int base = start; base < end; base += 512) {
        int gid = base + tid;
        if (gid < end) {
            int d = __builtin_nontemporal_load(&ei[E + gid]);
            int s = __builtin_nontemporal_load(&ei[gid]);
            int b = d >> BSHIFT;
            int val = ((d & 127) << 17) | s;
            int pos = atomicAdd(&lcnt[b], 1);
            if (pos < LCAP) {
                lbuf[b * LCAP + pos] = val;
            } else {
                // overflow fallback (P ~ 1e-7 per cell-batch): direct scatter
                int sb = b * NSUB + slice;
                int gp = atomicAdd(&cur[sb], 1);
                if (gp < SUBCAP) pairs[(size_t)sb * SUBCAP + gp] = val;
            }
        }
        __syncthreads();
        // flush full FCH-chunks; keep remainder (< FCH after flush) staged
        for (int b = tid; b < nbuck; b += 512) {
            int c = min(lcnt[b], LCAP);
            int nf = (c / FCH) * FCH;
            if (nf > 0) {
                int sb = b * NSUB + slice;
                int gbase = atomicAdd(&cur[sb], nf);
                int* dst = pairs + (size_t)sb * SUBCAP + gbase;
                if ((gbase & 3) == 0 && gbase + nf <= SUBCAP) {
                    #pragma unroll
                    for (int i = 0; i < LCAP; i += 4) {
                        if (i >= nf) break;
                        *(int4*)(dst + i) = *(int4*)(lbuf + b * LCAP + i);
                    }
                } else {
                    for (int i = 0; i < nf; ++i)
                        if (gbase + i < SUBCAP) dst[i] = lbuf[b * LCAP + i];
                }
                int rem = c - nf;
                for (int i = 0; i < rem; ++i)
                    lbuf[b * LCAP + i] = lbuf[b * LCAP + nf + i];
                lcnt[b] = rem;
            } else {
                lcnt[b] = c;   // clamp (entries >= LCAP went via fallback)
            }
        }
        __syncthreads();
    }

    // drain residuals (avg ~4 ints per non-empty cell)
    for (int b = tid; b < nbuck; b += 512) {
        int c = min(lcnt[b], LCAP);
        if (c > 0) {
            int sb = b * NSUB + slice;
            int gbase = atomicAdd(&cur[sb], c);
            for (int i = 0; i < c; ++i)
                if (gbase + i < SUBCAP)
                    pairs[(size_t)sb * SUBCAP + gbase + i] = lbuf[b * LCAP + i];
        }
    }
}

// ---------------------------------------------------------------------------
// Exclusive scan over per-bucket totals (sum of 8 sub-counts).  One block.
// ---------------------------------------------------------------------------
__global__ __launch_bounds__(1024) void bucket_scan(
    const int* __restrict__ cur, int* __restrict__ bbase, int nbuck)
{
    __shared__ int buf[1024];
    int tid = threadIdx.x;
    int v = 0;
    if (tid < nbuck) {
        #pragma unroll
        for (int s = 0; s < NSUB; ++s) v += min(cur[tid * NSUB + s], SUBCAP);
    }
    buf[tid] = v;
    __syncthreads();
    for (int off = 1; off < 1024; off <<= 1) {
        int t = (tid >= off) ? buf[tid - off] : 0;
        __syncthreads();
        buf[tid] += t;
        __syncthreads();
    }
    if (tid < nbuck) bbase[tid] = buf[tid] - v;   // exclusive prefix
}

// ---------------------------------------------------------------------------
// Per-bucket local CSR: concat 8 sub-lists into LDS -> LDS hist over the
// bucket's 128 nodes -> LDS scan -> LDS scatter -> coalesced csr write.
// Writes rs as global INCLUSIVE prefix.
// ---------------------------------------------------------------------------
__global__ __launch_bounds__(256) void local_fill(
    const int* __restrict__ cur, const int* __restrict__ bbase,
    const int* __restrict__ pairs, int* __restrict__ csr,
    int* __restrict__ rs, int N)
{
    __shared__ int ldata[CAP];                  // 10 KB packed pairs
    __shared__ int outsrc[CAP];                 // 10 KB scattered srcs
    __shared__ int lcnt[128], lofs[128], lincl[128];

    int b = blockIdx.x;
    int tid = threadIdx.x;
    int base = bbase[b];
    int node0 = b << BSHIFT;

    // concat sub-lists
    int off = 0;
    #pragma unroll
    for (int s = 0; s < NSUB; ++s) {
        int c = min(cur[b * NSUB + s], SUBCAP);
        const int* pp = pairs + (size_t)(b * NSUB + s) * SUBCAP;
        for (int i = tid; i < c && off + i < CAP; i += 256)
            ldata[off + i] = pp[i];
        off += c;
    }
    int cnt = min(off, CAP);
    __syncthreads();

    if (tid < 128) lcnt[tid] = 0;
    __syncthreads();
    for (int i = tid; i < cnt; i += 256)
        atomicAdd(&lcnt[ldata[i] >> 17], 1);
    __syncthreads();

    // inclusive scan of lcnt over 128 entries
    if (tid < 128) lincl[tid] = lcnt[tid];
    __syncthreads();
    for (int off2 = 1; off2 < 128; off2 <<= 1) {
        int t = 0;
        if (tid < 128 && tid >= off2) t = lincl[tid - off2];
        __syncthreads();
        if (tid < 128) lincl[tid] += t;
        __syncthreads();
    }
    if (tid < 128) lofs[tid] = lincl[tid] - lcnt[tid];  // exclusive
    __syncthreads();

    for (int i = tid; i < cnt; i += 256) {
        int v = ldata[i];
        int p = atomicAdd(&lofs[v >> 17], 1);
        outsrc[p] = v & 0x1FFFF;
    }
    __syncthreads();

    for (int i = tid; i < cnt; i += 256)        // coalesced
        csr[base + i] = outsrc[i];
    int nn = N - node0; if (nn > 128) nn = 128;
    if (tid < nn) rs[node0 + tid] = base + lincl[tid];
}

// ---------------------------------------------------------------------------
// Gather + GIN combine: acc = sum_j xb[src_j]; u = (1+eps)*xb[node] + acc,
// bf16 out.  csr via regular loads (4x intra-line reuse).  32 lanes/node.
// ---------------------------------------------------------------------------
__global__ __launch_bounds__(256) void gather_kernel(
    const unsigned short* __restrict__ xb, const float* __restrict__ epsp,
    const int* __restrict__ rs, const int* __restrict__ csr,
    unsigned short* __restrict__ ub, int N)
{
    int sub  = threadIdx.x >> 5;
    int lane = threadIdx.x & 31;
    int node = blockIdx.x * 8 + sub;
    if (node >= N) return;

    int start = (node == 0) ? 0 : rs[node - 1];
    int end   = rs[node];

    float4 acc = make_float4(0.f, 0.f, 0.f, 0.f);
    union { unsigned int u; float f; } c;
    #define BF2F(us) (c.u = ((unsigned int)(us)) << 16, c.f)

    int j = start;
    for (; j + 3 < end; j += 4) {
        int s0 = csr[j], s1 = csr[j + 1], s2 = csr[j + 2], s3 = csr[j + 3];
        ushort4 v0 = ((const ushort4*)(xb + (size_t)s0 * D))[lane];
        ushort4 v1 = ((const ushort4*)(xb + (size_t)s1 * D))[lane];
        ushort4 v2 = ((const ushort4*)(xb + (size_t)s2 * D))[lane];
        ushort4 v3 = ((const ushort4*)(xb + (size_t)s3 * D))[lane];
        acc.x += (BF2F(v0.x) + BF2F(v1.x)) + (BF2F(v2.x) + BF2F(v3.x));
        acc.y += (BF2F(v0.y) + BF2F(v1.y)) + (BF2F(v2.y) + BF2F(v3.y));
        acc.z += (BF2F(v0.z) + BF2F(v1.z)) + (BF2F(v2.z) + BF2F(v3.z));
        acc.w += (BF2F(v0.w) + BF2F(v1.w)) + (BF2F(v2.w) + BF2F(v3.w));
    }
    for (; j < end; ++j) {
        ushort4 v0 = ((const ushort4*)(xb + (size_t)csr[j] * D))[lane];
        acc.x += BF2F(v0.x); acc.y += BF2F(v0.y);
        acc.z += BF2F(v0.z); acc.w += BF2F(v0.w);
    }

    float ep1 = 1.0f + epsp[0];
    ushort4 xr = ((const ushort4*)(xb + (size_t)node * D))[lane];
    acc.x = fmaf(ep1, BF2F(xr.x), acc.x);
    acc.y = fmaf(ep1, BF2F(xr.y), acc.y);
    acc.z = fmaf(ep1, BF2F(xr.z), acc.z);
    acc.w = fmaf(ep1, BF2F(xr.w), acc.w);
    #undef BF2F
    ushort4 o;
    o.x = f2bf(acc.x); o.y = f2bf(acc.y); o.z = f2bf(acc.z); o.w = f2bf(acc.w);
    ((ushort4*)(ub + (size_t)node * D))[lane] = o;
}

// ---------------------------------------------------------------------------
// Fused 2-layer MLP (bf16 MFMA), round-8 verified.
// ---------------------------------------------------------------------------
__global__ __launch_bounds__(256, 2) void mlp_fused(
    const unsigned short* __restrict__ in,
    const unsigned short* __restrict__ W1t, const float* __restrict__ b1,
    const unsigned short* __restrict__ W2t, const float* __restrict__ b2,
    float* __restrict__ out, int N)
{
    __shared__ unsigned short Wl[128 * LDSPITCH];  // 34816 B
    __shared__ unsigned short Al[64 * LDSPITCH];   // 17408 B

    int tid = threadIdx.x;
    int row0 = blockIdx.x * 64;
    int wave = tid >> 6, lane = tid & 63;
    int l16 = lane & 15, lq = lane >> 4;

    for (int i = tid; i < 128 * 16; i += 256) {
        int r = i >> 4, cc = i & 15;
        ((int4*)(Wl + r * LDSPITCH))[cc] = ((const int4*)(W1t + r * 128))[cc];
    }
    for (int i = tid; i < 64 * 16; i += 256) {
        int r = i >> 4, cc = i & 15;
        int4 v = make_int4(0, 0, 0, 0);
        if (row0 + r < N) v = ((const int4*)(in + (size_t)(row0 + r) * 128))[cc];
        ((int4*)(Al + r * LDSPITCH))[cc] = v;
    }
    __syncthreads();

    f32x4 acc[8];
    #pragma unroll
    for (int t = 0; t < 8; ++t) acc[t] = (f32x4){0.f, 0.f, 0.f, 0.f};

    int arow = wave * 16 + l16;
    #pragma unroll
    for (int kk = 0; kk < 4; ++kk) {
        int k0 = kk * 32 + lq * 8;
        bf16x8 a = *(const bf16x8*)(Al + arow * LDSPITCH + k0);
        #pragma unroll
        for (int t = 0; t < 8; ++t) {
            bf16x8 b = *(const bf16x8*)(Wl + (t * 16 + l16) * LDSPITCH + k0);
            acc[t] = __builtin_amdgcn_mfma_f32_16x16x32_bf16(a, b, acc[t], 0, 0, 0);
        }
    }
    __syncthreads();

    for (int i = tid; i < 128 * 16; i += 256) {
        int r = i >> 4, cc = i & 15;
        ((int4*)(Wl + r * LDSPITCH))[cc] = ((const int4*)(W2t + r * 128))[cc];
    }
    #pragma unroll
    for (int t = 0; t < 8; ++t) {
        int col = t * 16 + l16;
        float bv = b1[col];
        #pragma unroll
        for (int r = 0; r < 4; ++r) {
            int row = wave * 16 + lq * 4 + r;
            float v = fmaxf(acc[t][r] + bv, 0.0f);
            Al[row * LDSPITCH + col] = f2bf(v);
        }
    }
    __syncthreads();

    #pragma unroll
    for (int t = 0; t < 8; ++t) acc[t] = (f32x4){0.f, 0.f, 0.f, 0.f};
    #pragma unroll
    for (int kk = 0; kk < 4; ++kk) {
        int k0 = kk * 32 + lq * 8;
        bf16x8 a = *(const bf16x8*)(Al + arow * LDSPITCH + k0);
        #pragma unroll
        for (int t = 0; t < 8; ++t) {
            bf16x8 b = *(const bf16x8*)(Wl + (t * 16 + l16) * LDSPITCH + k0);
            acc[t] = __builtin_amdgcn_mfma_f32_16x16x32_bf16(a, b, acc[t], 0, 0, 0);
        }
    }

    #pragma unroll
    for (int t = 0; t < 8; ++t) {
        int col = t * 16 + l16;
        float bv = b2[col];
        #pragma unroll
        for (int r = 0; r < 4; ++r) {
            int row = row0 + wave * 16 + lq * 4 + r;
            if (row >= N) continue;
            out[(size_t)row * 128 + col] = acc[t][r] + bv;
        }
    }
}

extern "C" void kernel_launch(void* const* d_in, const int* in_sizes, int n_in,
                              void* d_out, int out_size, void* d_ws, size_t ws_size,
                              hipStream_t stream) {
    const float* x   = (const float*)d_in[0];
    const int*   ei  = (const int*)d_in[1];    // edge_index [2][E]
    const float* eps = (const float*)d_in[2];
    const float* W1  = (const float*)d_in[3];
    const float* b1  = (const float*)d_in[4];
    const float* W2  = (const float*)d_in[5];
    const float* b2  = (const float*)d_in[6];
    float* out = (float*)d_out;

    int E = in_sizes[1] / 2;                   // 1,600,000
    int N = in_sizes[0] / D;                   // 100,000
    int nbuck = (N + 127) >> BSHIFT;           // 782

    // workspace layout (bytes):
    //   [0, 28672)               cur   int[nbuck*8]   (25,024 used)
    //   [28672, 32768)           bbase int[nbuck]
    //   [32768, 432768)          rs    int[N]
    //   [434176, 10043392)       pairs int[nbuck*8*SUBCAP]  (9.6 MB)
    //   [10044416, 16444416)     csr   int[E]
    //   [16445440, 42045440)     xb    bf16[N*D]
    //   [42046464, 67646464)     ub    bf16[N*D]
    //   [67647488, +32768)       W1t   bf16[128*128]
    //   [67680256, +32768)       W2t   bf16[128*128]
    char* ws = (char*)d_ws;
    int* cur   = (int*)(ws);
    int* bbase = (int*)(ws + 28672);
    int* rs    = (int*)(ws + 32768);
    int* pairs = (int*)(ws + 434176);
    int* csr   = (int*)(ws + 10044416);
    unsigned short* xb  = (unsigned short*)(ws + 16445440);
    unsigned short* ub  = (unsigned short*)(ws + 42046464);
    unsigned short* W1t = (unsigned short*)(ws + 67647488);
    unsigned short* W2t = (unsigned short*)(ws + 67680256);

    hipMemsetAsync(cur, 0, (size_t)nbuck * NSUB * sizeof(int), stream);

    int total4 = N * D / 4;
    convert_kernel<<<(total4 + 255) / 256, 256, 0, stream>>>(x, xb, total4);
    convw_kernel<<<64, 256, 0, stream>>>(W1, W1t);
    convw_kernel<<<64, 256, 0, stream>>>(W2, W2t);

    bin_kernel<<<128, 512, 0, stream>>>(ei, cur, pairs, E, nbuck);
    bucket_scan<<<1, 1024, 0, stream>>>(cur, bbase, nbuck);
    local_fill<<<nbuck, 256, 0, stream>>>(cur, bbase, pairs, csr, rs, N);

    gather_kernel<<<(N + 7) / 8, 256, 0, stream>>>(xb, eps, rs, csr, ub, N);

    int gemm_blocks = (N + 63) / 64;           // 1563
    mlp_fused<<<gemm_blocks, 256, 0, stream>>>(ub, W1t, b1, W2t, b2, out, N);
}

// Round 2
// 279.443 us; speedup vs baseline: 1.1178x; 1.0211x over previous
//
#include <hip/hip_runtime.h>

#define D 128
#define BSHIFT 7          // 128 nodes per bucket
#define NSUB 8            // sub-buckets per bucket, keyed by blockIdx&7 (XCD)
#define SUBCAP 384        // per-sub-bucket capacity: lambda=256, +8 sigma
#define CAP 2560          // whole-bucket LDS staging: lambda=2048, +11 sigma
#define LDSPITCH 136      // ushorts/row: 128+8 pad (2-way bank alias = free)

// bin_kernel LDS chunk staging
#define NBMAX 784         // >= nbuck (782), padded
#define LCAP 16           // ints staged per bucket in LDS
#define FCH 8             // flush granularity: 8 ints = 32 B = one L2 sector

typedef __attribute__((ext_vector_type(8))) short bf16x8;   // 8 bf16 = 4 VGPR
typedef __attribute__((ext_vector_type(4))) float f32x4;    // MFMA acc
typedef __attribute__((ext_vector_type(4))) unsigned int u32x4;

__device__ __forceinline__ unsigned short f2bf(float f) {   // fp32 -> bf16 RNE
    union { float f; unsigned int u; } c; c.f = f;
    return (unsigned short)((c.u + 0x7FFFu + ((c.u >> 16) & 1u)) >> 16);
}

// ---------------------------------------------------------------------------
// x (fp32) -> xb (bf16) for the gather.
// ---------------------------------------------------------------------------
__global__ __launch_bounds__(256) void convert_kernel(
    const float* __restrict__ x, unsigned short* __restrict__ xb, int total4)
{
    int gid = blockIdx.x * 256 + threadIdx.x;
    if (gid >= total4) return;
    float4 v = ((const float4*)x)[gid];
    ushort4 o;
    o.x = f2bf(v.x); o.y = f2bf(v.y); o.z = f2bf(v.z); o.w = f2bf(v.w);
    ((ushort4*)xb)[gid] = o;
}

// ---------------------------------------------------------------------------
// W [k][n] fp32 -> Wt [n][k] bf16.
// ---------------------------------------------------------------------------
__global__ __launch_bounds__(256) void convw_kernel(
    const float* __restrict__ W, unsigned short* __restrict__ Wt)
{
    int gid = blockIdx.x * 256 + threadIdx.x;   // 0..16383
    int n = gid >> 7, k = gid & 127;
    Wt[n * 128 + k] = f2bf(W[k * 128 + n]);
}

// ---------------------------------------------------------------------------
// Bucket binning, round-10: LDS chunk aggregation (verified round-1:
// bin dropped out of top-5; WRITE amplification gone).
// ---------------------------------------------------------------------------
__global__ __launch_bounds__(512) void bin_kernel(
    const int* __restrict__ ei, int* __restrict__ cur,
    int* __restrict__ pairs, int E, int nbuck)
{
    __shared__ int lbuf[NBMAX * LCAP];   // 50 KB
    __shared__ int lcnt[NBMAX];          // 3 KB

    int tid = threadIdx.x;
    int slice = blockIdx.x & (NSUB - 1);
    int nblocks = gridDim.x;
    int epb = (E + nblocks - 1) / nblocks;
    int start = blockIdx.x * epb;
    int end = min(start + epb, E);

    for (int b = tid; b < nbuck; b += 512) lcnt[b] = 0;
    __syncthreads();

    for (int base = start; base < end; base += 512) {
        int gid = base + tid;
        if (gid < end) {
            int d = __builtin_nontemporal_load(&ei[E + gid]);
            int s = __builtin_nontemporal_load(&ei[gid]);
            int b = d >> BSHIFT;
            int val = ((d & 127) << 17) | s;
            int pos = atomicAdd(&lcnt[b], 1);
            if (pos < LCAP) {
                lbuf[b * LCAP + pos] = val;
            } else {
                // overflow fallback (P ~ 1e-7 per cell-batch): direct scatter
                int sb = b * NSUB + slice;
                int gp = atomicAdd(&cur[sb], 1);
                if (gp < SUBCAP) pairs[(size_t)sb * SUBCAP + gp] = val;
            }
        }
        __syncthreads();
        // flush full FCH-chunks; keep remainder (< FCH after flush) staged
        for (int b = tid; b < nbuck; b += 512) {
            int c = min(lcnt[b], LCAP);
            int nf = (c / FCH) * FCH;
            if (nf > 0) {
                int sb = b * NSUB + slice;
                int gbase = atomicAdd(&cur[sb], nf);
                int* dst = pairs + (size_t)sb * SUBCAP + gbase;
                if ((gbase & 3) == 0 && gbase + nf <= SUBCAP) {
                    #pragma unroll
                    for (int i = 0; i < LCAP; i += 4) {
                        if (i >= nf) break;
                        *(int4*)(dst + i) = *(int4*)(lbuf + b * LCAP + i);
                    }
                } else {
                    for (int i = 0; i < nf; ++i)
                        if (gbase + i < SUBCAP) dst[i] = lbuf[b * LCAP + i];
                }
                int rem = c - nf;
                for (int i = 0; i < rem; ++i)
                    lbuf[b * LCAP + i] = lbuf[b * LCAP + nf + i];
                lcnt[b] = rem;
            } else {
                lcnt[b] = c;   // clamp (entries >= LCAP went via fallback)
            }
        }
        __syncthreads();
    }

    // drain residuals (avg ~4 ints per non-empty cell)
    for (int b = tid; b < nbuck; b += 512) {
        int c = min(lcnt[b], LCAP);
        if (c > 0) {
            int sb = b * NSUB + slice;
            int gbase = atomicAdd(&cur[sb], c);
            for (int i = 0; i < c; ++i)
                if (gbase + i < SUBCAP)
                    pairs[(size_t)sb * SUBCAP + gbase + i] = lbuf[b * LCAP + i];
        }
    }
}

// ---------------------------------------------------------------------------
// Exclusive scan over per-bucket totals (sum of 8 sub-counts).  One block.
// ---------------------------------------------------------------------------
__global__ __launch_bounds__(1024) void bucket_scan(
    const int* __restrict__ cur, int* __restrict__ bbase, int nbuck)
{
    __shared__ int buf[1024];
    int tid = threadIdx.x;
    int v = 0;
    if (tid < nbuck) {
        #pragma unroll
        for (int s = 0; s < NSUB; ++s) v += min(cur[tid * NSUB + s], SUBCAP);
    }
    buf[tid] = v;
    __syncthreads();
    for (int off = 1; off < 1024; off <<= 1) {
        int t = (tid >= off) ? buf[tid - off] : 0;
        __syncthreads();
        buf[tid] += t;
        __syncthreads();
    }
    if (tid < nbuck) bbase[tid] = buf[tid] - v;   // exclusive prefix
}

// ---------------------------------------------------------------------------
// Per-bucket local CSR: concat 8 sub-lists into LDS -> LDS hist over the
// bucket's 128 nodes -> LDS scan -> LDS scatter -> coalesced csr write.
// Writes rs as global INCLUSIVE prefix.
// ---------------------------------------------------------------------------
__global__ __launch_bounds__(256) void local_fill(
    const int* __restrict__ cur, const int* __restrict__ bbase,
    const int* __restrict__ pairs, int* __restrict__ csr,
    int* __restrict__ rs, int N)
{
    __shared__ int ldata[CAP];                  // 10 KB packed pairs
    __shared__ int outsrc[CAP];                 // 10 KB scattered srcs
    __shared__ int lcnt[128], lofs[128], lincl[128];

    int b = blockIdx.x;
    int tid = threadIdx.x;
    int base = bbase[b];
    int node0 = b << BSHIFT;

    // concat sub-lists
    int off = 0;
    #pragma unroll
    for (int s = 0; s < NSUB; ++s) {
        int c = min(cur[b * NSUB + s], SUBCAP);
        const int* pp = pairs + (size_t)(b * NSUB + s) * SUBCAP;
        for (int i = tid; i < c && off + i < CAP; i += 256)
            ldata[off + i] = pp[i];
        off += c;
    }
    int cnt = min(off, CAP);
    __syncthreads();

    if (tid < 128) lcnt[tid] = 0;
    __syncthreads();
    for (int i = tid; i < cnt; i += 256)
        atomicAdd(&lcnt[ldata[i] >> 17], 1);
    __syncthreads();

    // inclusive scan of lcnt over 128 entries
    if (tid < 128) lincl[tid] = lcnt[tid];
    __syncthreads();
    for (int off2 = 1; off2 < 128; off2 <<= 1) {
        int t = 0;
        if (tid < 128 && tid >= off2) t = lincl[tid - off2];
        __syncthreads();
        if (tid < 128) lincl[tid] += t;
        __syncthreads();
    }
    if (tid < 128) lofs[tid] = lincl[tid] - lcnt[tid];  // exclusive
    __syncthreads();

    for (int i = tid; i < cnt; i += 256) {
        int v = ldata[i];
        int p = atomicAdd(&lofs[v >> 17], 1);
        outsrc[p] = v & 0x1FFFF;
    }
    __syncthreads();

    for (int i = tid; i < cnt; i += 256)        // coalesced
        csr[base + i] = outsrc[i];
    int nn = N - node0; if (nn > 128) nn = 128;
    if (tid < nn) rs[node0 + tid] = base + lincl[tid];
}

// ---------------------------------------------------------------------------
// Gather + GIN combine, round-11: 2-edges-per-load pipeline.
// Round-1 counters: 67 us, FETCH 187 MB (= per-XCD compulsory floor for a
// random gather: 8 XCDs x 25.6 MB table), VALUBusy 31% -> latency/issue
// bound, not fetch-bound.  Restructure: 32 lanes/node, but each load instr
// covers TWO edges (lanes 0-15 = edge j, 16-31 = edge j+1, ushort8 = 16 B
// per lane), unrolled to 8 edges / 4 loads in flight (2 KB outstanding per
// sub-warp, was 1 KB; load+address instr count per edge halved).  Self term
// (1+eps)*x[node] folded into the acc init of the hi==0 half (latency hides
// under the loop).  Halves combined at the end with 8 shfl_xor(16).
// ---------------------------------------------------------------------------
__global__ __launch_bounds__(256) void gather_kernel(
    const unsigned short* __restrict__ xb, const float* __restrict__ epsp,
    const int* __restrict__ rs, const int* __restrict__ csr,
    unsigned short* __restrict__ ub, int N)
{
    int sub  = threadIdx.x >> 5;          // 8 nodes / block
    int lane = threadIdx.x & 31;
    int hi   = lane >> 4;                 // which edge of the pair
    int c16  = lane & 15;                 // 16-B chunk within the row
    int node = blockIdx.x * 8 + sub;
    if (node >= N) return;

    int start = (node == 0) ? 0 : rs[node - 1];
    int end   = rs[node];
    int boff  = c16 * 8;                  // ushort offset of this lane's chunk

    float acc[8];
    {   // init: hi==0 lanes carry the (1+eps)*x self term, hi==1 start at 0
        float ep1 = 1.0f + epsp[0];
        u32x4 xr = *(const u32x4*)(xb + (size_t)node * D + boff);
        #pragma unroll
        for (int e = 0; e < 4; ++e) {
            unsigned int w = xr[e];
            float lo = __uint_as_float(w << 16);
            float hf = __uint_as_float(w & 0xFFFF0000u);
            acc[2 * e]     = hi ? 0.f : ep1 * lo;
            acc[2 * e + 1] = hi ? 0.f : ep1 * hf;
        }
    }

    #define ACC8(v)                                                         \
        {                                                                   \
            _Pragma("unroll")                                               \
            for (int e = 0; e < 4; ++e) {                                   \
                unsigned int w = (v)[e];                                    \
                acc[2 * e]     += __uint_as_float(w << 16);                 \
                acc[2 * e + 1] += __uint_as_float(w & 0xFFFF0000u);         \
            }                                                               \
        }

    int j = start;
    for (; j + 8 <= end; j += 8) {        // 8 edges per iter, 4 loads in flight
        int s0 = csr[j     + hi];
        int s1 = csr[j + 2 + hi];
        int s2 = csr[j + 4 + hi];
        int s3 = csr[j + 6 + hi];
        u32x4 v0 = *(const u32x4*)(xb + (size_t)s0 * D + boff);
        u32x4 v1 = *(const u32x4*)(xb + (size_t)s1 * D + boff);
        u32x4 v2 = *(const u32x4*)(xb + (size_t)s2 * D + boff);
        u32x4 v3 = *(const u32x4*)(xb + (size_t)s3 * D + boff);
        ACC8(v0); ACC8(v1); ACC8(v2); ACC8(v3);
    }
    for (; j < end; j += 2) {             // tail: 2 edges, hi half masked if odd
        int idx = j + hi;
        if (idx < end) {
            int s = csr[idx];
            u32x4 v = *(const u32x4*)(xb + (size_t)s * D + boff);
            ACC8(v);
        }
    }
    #undef ACC8

    // combine the two 16-lane halves (same column set, disjoint edge subsets)
    #pragma unroll
    for (int e = 0; e < 8; ++e) acc[e] += __shfl_xor(acc[e], 16);

    if (hi == 0) {                        // 16 lanes x 16 B = full row
        u32x4 o;
        #pragma unroll
        for (int e = 0; e < 4; ++e) {
            unsigned int lo = f2bf(acc[2 * e]);
            unsigned int hf = f2bf(acc[2 * e + 1]);
            o[e] = lo | (hf << 16);
        }
        *(u32x4*)(ub + (size_t)node * D + boff) = o;
    }
}

// ---------------------------------------------------------------------------
// Fused 2-layer MLP (bf16 MFMA), round-8 verified.
// ---------------------------------------------------------------------------
__global__ __launch_bounds__(256, 2) void mlp_fused(
    const unsigned short* __restrict__ in,
    const unsigned short* __restrict__ W1t, const float* __restrict__ b1,
    const unsigned short* __restrict__ W2t, const float* __restrict__ b2,
    float* __restrict__ out, int N)
{
    __shared__ unsigned short Wl[128 * LDSPITCH];  // 34816 B
    __shared__ unsigned short Al[64 * LDSPITCH];   // 17408 B

    int tid = threadIdx.x;
    int row0 = blockIdx.x * 64;
    int wave = tid >> 6, lane = tid & 63;
    int l16 = lane & 15, lq = lane >> 4;

    for (int i = tid; i < 128 * 16; i += 256) {
        int r = i >> 4, cc = i & 15;
        ((int4*)(Wl + r * LDSPITCH))[cc] = ((const int4*)(W1t + r * 128))[cc];
    }
    for (int i = tid; i < 64 * 16; i += 256) {
        int r = i >> 4, cc = i & 15;
        int4 v = make_int4(0, 0, 0, 0);
        if (row0 + r < N) v = ((const int4*)(in + (size_t)(row0 + r) * 128))[cc];
        ((int4*)(Al + r * LDSPITCH))[cc] = v;
    }
    __syncthreads();

    f32x4 acc[8];
    #pragma unroll
    for (int t = 0; t < 8; ++t) acc[t] = (f32x4){0.f, 0.f, 0.f, 0.f};

    int arow = wave * 16 + l16;
    #pragma unroll
    for (int kk = 0; kk < 4; ++kk) {
        int k0 = kk * 32 + lq * 8;
        bf16x8 a = *(const bf16x8*)(Al + arow * LDSPITCH + k0);
        #pragma unroll
        for (int t = 0; t < 8; ++t) {
            bf16x8 b = *(const bf16x8*)(Wl + (t * 16 + l16) * LDSPITCH + k0);
            acc[t] = __builtin_amdgcn_mfma_f32_16x16x32_bf16(a, b, acc[t], 0, 0, 0);
        }
    }
    __syncthreads();

    for (int i = tid; i < 128 * 16; i += 256) {
        int r = i >> 4, cc = i & 15;
        ((int4*)(Wl + r * LDSPITCH))[cc] = ((const int4*)(W2t + r * 128))[cc];
    }
    #pragma unroll
    for (int t = 0; t < 8; ++t) {
        int col = t * 16 + l16;
        float bv = b1[col];
        #pragma unroll
        for (int r = 0; r < 4; ++r) {
            int row = wave * 16 + lq * 4 + r;
            float v = fmaxf(acc[t][r] + bv, 0.0f);
            Al[row * LDSPITCH + col] = f2bf(v);
        }
    }
    __syncthreads();

    #pragma unroll
    for (int t = 0; t < 8; ++t) acc[t] = (f32x4){0.f, 0.f, 0.f, 0.f};
    #pragma unroll
    for (int kk = 0; kk < 4; ++kk) {
        int k0 = kk * 32 + lq * 8;
        bf16x8 a = *(const bf16x8*)(Al + arow * LDSPITCH + k0);
        #pragma unroll
        for (int t = 0; t < 8; ++t) {
            bf16x8 b = *(const bf16x8*)(Wl + (t * 16 + l16) * LDSPITCH + k0);
            acc[t] = __builtin_amdgcn_mfma_f32_16x16x32_bf16(a, b, acc[t], 0, 0, 0);
        }
    }

    #pragma unroll
    for (int t = 0; t < 8; ++t) {
        int col = t * 16 + l16;
        float bv = b2[col];
        #pragma unroll
        for (int r = 0; r < 4; ++r) {
            int row = row0 + wave * 16 + lq * 4 + r;
            if (row >= N) continue;
            out[(size_t)row * 128 + col] = acc[t][r] + bv;
        }
    }
}

extern "C" void kernel_launch(void* const* d_in, const int* in_sizes, int n_in,
                              void* d_out, int out_size, void* d_ws, size_t ws_size,
                              hipStream_t stream) {
    const float* x   = (const float*)d_in[0];
    const int*   ei  = (const int*)d_in[1];    // edge_index [2][E]
    const float* eps = (const float*)d_in[2];
    const float* W1  = (const float*)d_in[3];
    const float* b1  = (const float*)d_in[4];
    const float* W2  = (const float*)d_in[5];
    const float* b2  = (const float*)d_in[6];
    float* out = (float*)d_out;

    int E = in_sizes[1] / 2;                   // 1,600,000
    int N = in_sizes[0] / D;                   // 100,000
    int nbuck = (N + 127) >> BSHIFT;           // 782

    // workspace layout (bytes):
    //   [0, 28672)               cur   int[nbuck*8]   (25,024 used)
    //   [28672, 32768)           bbase int[nbuck]
    //   [32768, 432768)          rs    int[N]
    //   [434176, 10043392)       pairs int[nbuck*8*SUBCAP]  (9.6 MB)
    //   [10044416, 16444416)     csr   int[E]
    //   [16445440, 42045440)     xb    bf16[N*D]
    //   [42046464, 67646464)     ub    bf16[N*D]
    //   [67647488, +32768)       W1t   bf16[128*128]
    //   [67680256, +32768)       W2t   bf16[128*128]
    char* ws = (char*)d_ws;
    int* cur   = (int*)(ws);
    int* bbase = (int*)(ws + 28672);
    int* rs    = (int*)(ws + 32768);
    int* pairs = (int*)(ws + 434176);
    int* csr   = (int*)(ws + 10044416);
    unsigned short* xb  = (unsigned short*)(ws + 16445440);
    unsigned short* ub  = (unsigned short*)(ws + 42046464);
    unsigned short* W1t = (unsigned short*)(ws + 67647488);
    unsigned short* W2t = (unsigned short*)(ws + 67680256);

    hipMemsetAsync(cur, 0, (size_t)nbuck * NSUB * sizeof(int), stream);

    int total4 = N * D / 4;
    convert_kernel<<<(total4 + 255) / 256, 256, 0, stream>>>(x, xb, total4);
    convw_kernel<<<64, 256, 0, stream>>>(W1, W1t);
    convw_kernel<<<64, 256, 0, stream>>>(W2, W2t);

    bin_kernel<<<128, 512, 0, stream>>>(ei, cur, pairs, E, nbuck);
    bucket_scan<<<1, 1024, 0, stream>>>(cur, bbase, nbuck);
    local_fill<<<nbuck, 256, 0, stream>>>(cur, bbase, pairs, csr, rs, N);

    gather_kernel<<<(N + 7) / 8, 256, 0, stream>>>(xb, eps, rs, csr, ub, N);

    int gemm_blocks = (N + 63) / 64;           // 1563
    mlp_fused<<<gemm_blocks, 256, 0, stream>>>(ub, W1t, b1, W2t, b2, out, N);
}

// Round 3
// 256.182 us; speedup vs baseline: 1.2193x; 1.0908x over previous
//
#include <hip/hip_runtime.h>

#define D 128
#define BSHIFT 7          // 128 nodes per bucket
#define NSUB 8            // sub-buckets per bucket, keyed by blockIdx&7 (XCD)
#define SUBCAP 384        // per-sub-bucket capacity: lambda=256, +8 sigma
#define CAP 2560          // whole-bucket LDS staging: lambda=2048, +11 sigma
#define LDSPITCH 136      // ushorts/row: 128+8 pad (2-way bank alias = free)

// bin_kernel LDS chunk staging
#define NBMAX 784         // >= nbuck (782), padded
#define LCAP 16           // ints staged per bucket in LDS
#define FCH 8             // flush granularity: 8 ints = 32 B = one L2 sector

typedef __attribute__((ext_vector_type(8))) short bf16x8;   // 8 bf16 = 4 VGPR
typedef __attribute__((ext_vector_type(4))) float f32x4;    // MFMA acc
typedef __attribute__((ext_vector_type(2))) float f32x2;    // pk_add pair
typedef __attribute__((ext_vector_type(4))) unsigned int u32x4;

__device__ __forceinline__ unsigned short f2bf(float f) {   // fp32 -> bf16 RNE
    union { float f; unsigned int u; } c; c.f = f;
    return (unsigned short)((c.u + 0x7FFFu + ((c.u >> 16) & 1u)) >> 16);
}

// ---------------------------------------------------------------------------
// Fused prologue (round-12, launch-count cut 9->5): x->bf16 convert,
// W1/W2 transpose+convert, and cur[] zeroing in ONE dispatch.
// Work layout: [0,total4) convert, then 16384 W1t, 16384 W2t, then ncur zero.
// ---------------------------------------------------------------------------
__global__ __launch_bounds__(256) void conv_all(
    const float* __restrict__ x, unsigned short* __restrict__ xb,
    const float* __restrict__ W1, unsigned short* __restrict__ W1t,
    const float* __restrict__ W2, unsigned short* __restrict__ W2t,
    int* __restrict__ cur, int total4, int ncur)
{
    int gid = blockIdx.x * 256 + threadIdx.x;
    if (gid < total4) {
        float4 v = ((const float4*)x)[gid];
        ushort4 o;
        o.x = f2bf(v.x); o.y = f2bf(v.y); o.z = f2bf(v.z); o.w = f2bf(v.w);
        ((ushort4*)xb)[gid] = o;
        return;
    }
    int r = gid - total4;
    if (r < 16384) {
        int n = r >> 7, k = r & 127;
        W1t[n * 128 + k] = f2bf(W1[k * 128 + n]);
        return;
    }
    r -= 16384;
    if (r < 16384) {
        int n = r >> 7, k = r & 127;
        W2t[n * 128 + k] = f2bf(W2[k * 128 + n]);
        return;
    }
    r -= 16384;
    if (r < ncur) cur[r] = 0;
}

// ---------------------------------------------------------------------------
// Bucket binning: LDS chunk aggregation (round-10, verified: WRITE
// amplification gone).  Round-12: grid 128->256 blocks — at 53 KB LDS only
// 1 block/CU fits concurrently per 2 CUs' worth before; 128 blocks used
// half the chip.  256 blocks = all CUs; slice = blockIdx&7 XCD map kept.
// ---------------------------------------------------------------------------
__global__ __launch_bounds__(512) void bin_kernel(
    const int* __restrict__ ei, int* __restrict__ cur,
    int* __restrict__ pairs, int E, int nbuck)
{
    __shared__ int lbuf[NBMAX * LCAP];   // 50 KB
    __shared__ int lcnt[NBMAX];          // 3 KB

    int tid = threadIdx.x;
    int slice = blockIdx.x & (NSUB - 1);
    int nblocks = gridDim.x;
    int epb = (E + nblocks - 1) / nblocks;
    int start = blockIdx.x * epb;
    int end = min(start + epb, E);

    for (int b = tid; b < nbuck; b += 512) lcnt[b] = 0;
    __syncthreads();

    for (int base = start; base < end; base += 512) {
        int gid = base + tid;
        if (gid < end) {
            int d = __builtin_nontemporal_load(&ei[E + gid]);
            int s = __builtin_nontemporal_load(&ei[gid]);
            int b = d >> BSHIFT;
            int val = ((d & 127) << 17) | s;
            int pos = atomicAdd(&lcnt[b], 1);
            if (pos < LCAP) {
                lbuf[b * LCAP + pos] = val;
            } else {
                // overflow fallback: direct scatter
                int sb = b * NSUB + slice;
                int gp = atomicAdd(&cur[sb], 1);
                if (gp < SUBCAP) pairs[(size_t)sb * SUBCAP + gp] = val;
            }
        }
        __syncthreads();
        // flush full FCH-chunks; keep remainder (< FCH after flush) staged
        for (int b = tid; b < nbuck; b += 512) {
            int c = min(lcnt[b], LCAP);
            int nf = (c / FCH) * FCH;
            if (nf > 0) {
                int sb = b * NSUB + slice;
                int gbase = atomicAdd(&cur[sb], nf);
                int* dst = pairs + (size_t)sb * SUBCAP + gbase;
                if ((gbase & 3) == 0 && gbase + nf <= SUBCAP) {
                    #pragma unroll
                    for (int i = 0; i < LCAP; i += 4) {
                        if (i >= nf) break;
                        *(int4*)(dst + i) = *(int4*)(lbuf + b * LCAP + i);
                    }
                } else {
                    for (int i = 0; i < nf; ++i)
                        if (gbase + i < SUBCAP) dst[i] = lbuf[b * LCAP + i];
                }
                int rem = c - nf;
                for (int i = 0; i < rem; ++i)
                    lbuf[b * LCAP + i] = lbuf[b * LCAP + nf + i];
                lcnt[b] = rem;
            } else {
                lcnt[b] = c;   // clamp (entries >= LCAP went via fallback)
            }
        }
        __syncthreads();
    }

    // drain residuals
    for (int b = tid; b < nbuck; b += 512) {
        int c = min(lcnt[b], LCAP);
        if (c > 0) {
            int sb = b * NSUB + slice;
            int gbase = atomicAdd(&cur[sb], c);
            for (int i = 0; i < c; ++i)
                if (gbase + i < SUBCAP)
                    pairs[(size_t)sb * SUBCAP + gbase + i] = lbuf[b * LCAP + i];
        }
    }
}

// ---------------------------------------------------------------------------
// Per-bucket local CSR.  Round-12: bucket_scan dispatch eliminated — each
// block computes its own exclusive base by summing min(cur[sb],SUBCAP) over
// all sb < b*NSUB (<= 12.5 KB of L2-hot reads + 256-thread LDS reduce).
// Writes rs as global INCLUSIVE prefix.
// ---------------------------------------------------------------------------
__global__ __launch_bounds__(256) void local_fill(
    const int* __restrict__ cur, const int* __restrict__ pairs,
    int* __restrict__ csr, int* __restrict__ rs, int N)
{
    __shared__ int ldata[CAP];                  // 10 KB packed pairs
    __shared__ int outsrc[CAP];                 // 10 KB scattered srcs
    __shared__ int lcnt[128], lofs[128], lincl[128];
    __shared__ int red[256];

    int b = blockIdx.x;
    int tid = threadIdx.x;
    int node0 = b << BSHIFT;

    // exclusive base = sum of clamped sub-counts of all preceding buckets
    int pacc = 0;
    for (int i = tid; i < b * NSUB; i += 256) pacc += min(cur[i], SUBCAP);
    red[tid] = pacc;
    __syncthreads();
    for (int s = 128; s > 0; s >>= 1) {
        if (tid < s) red[tid] += red[tid + s];
        __syncthreads();
    }
    int base = red[0];

    // concat sub-lists
    int off = 0;
    #pragma unroll
    for (int s = 0; s < NSUB; ++s) {
        int c = min(cur[b * NSUB + s], SUBCAP);
        const int* pp = pairs + (size_t)(b * NSUB + s) * SUBCAP;
        for (int i = tid; i < c && off + i < CAP; i += 256)
            ldata[off + i] = pp[i];
        off += c;
    }
    int cnt = min(off, CAP);
    __syncthreads();

    if (tid < 128) lcnt[tid] = 0;
    __syncthreads();
    for (int i = tid; i < cnt; i += 256)
        atomicAdd(&lcnt[ldata[i] >> 17], 1);
    __syncthreads();

    // inclusive scan of lcnt over 128 entries
    if (tid < 128) lincl[tid] = lcnt[tid];
    __syncthreads();
    for (int off2 = 1; off2 < 128; off2 <<= 1) {
        int t = 0;
        if (tid < 128 && tid >= off2) t = lincl[tid - off2];
        __syncthreads();
        if (tid < 128) lincl[tid] += t;
        __syncthreads();
    }
    if (tid < 128) lofs[tid] = lincl[tid] - lcnt[tid];  // exclusive
    __syncthreads();

    for (int i = tid; i < cnt; i += 256) {
        int v = ldata[i];
        int p = atomicAdd(&lofs[v >> 17], 1);
        outsrc[p] = v & 0x1FFFF;
    }
    __syncthreads();

    for (int i = tid; i < cnt; i += 256)        // coalesced
        csr[base + i] = outsrc[i];
    int nn = N - node0; if (nn > 128) nn = 128;
    if (tid < nn) rs[node0 + tid] = base + lincl[tid];
}

// ---------------------------------------------------------------------------
// Gather + GIN combine, round-12: true 8-loads-in-flight pipeline.
// Round-2 evidence: VGPR=24 (4x data + 8 acc exactly) => compiler had no
// regs for addresses, real MLP ~2 loads, hence only 67->61 us.  v3: 16-edge
// main loop (8 row loads, 32 data VGPR; target total ~60 <= 64 so occupancy
// stays 32 waves/CU), branchless masked-8 tail (old 2-edge tail exposed a
// full memory latency per trip), float2 acc (v_pk_add_f32), nontemporal ub
// store (don't evict xb from L2 with the 25.6 MB output stream).
// ---------------------------------------------------------------------------
__global__ __launch_bounds__(256) void gather_kernel(
    const unsigned short* __restrict__ xb, const float* __restrict__ epsp,
    const int* __restrict__ rs, const int* __restrict__ csr,
    unsigned short* __restrict__ ub, int N)
{
    int sub  = threadIdx.x >> 5;          // 8 nodes / block
    int lane = threadIdx.x & 31;
    int hi   = lane >> 4;                 // which edge of the pair
    int c16  = lane & 15;                 // 16-B chunk within the row
    int node = blockIdx.x * 8 + sub;
    if (node >= N) return;

    int start = (node == 0) ? 0 : rs[node - 1];
    int end   = rs[node];
    int boff  = c16 * 8;                  // ushort offset of this lane's chunk

    f32x2 acc[4];
    {   // init: hi==0 lanes carry the (1+eps)*x self term, hi==1 start at 0
        float ep1 = 1.0f + epsp[0];
        u32x4 xr = *(const u32x4*)(xb + (size_t)node * D + boff);
        f32x2 z = {0.f, 0.f};
        #pragma unroll
        for (int e = 0; e < 4; ++e) {
            unsigned int w = xr[e];
            f32x2 t;
            t.x = __uint_as_float(w << 16);
            t.y = __uint_as_float(w & 0xFFFF0000u);
            acc[e] = hi ? z : (ep1 * t);
        }
    }

    #define ACC8(v)                                                         \
        {                                                                   \
            _Pragma("unroll")                                               \
            for (int e = 0; e < 4; ++e) {                                   \
                unsigned int w = (v)[e];                                    \
                f32x2 t;                                                    \
                t.x = __uint_as_float(w << 16);                             \
                t.y = __uint_as_float(w & 0xFFFF0000u);                     \
                acc[e] += t;                                                \
            }                                                               \
        }

    int j = start;
    for (; j + 16 <= end; j += 16) {      // 16 edges, 8 row loads in flight
        int i0 = csr[j      + hi], i1 = csr[j +  2 + hi];
        int i2 = csr[j +  4 + hi], i3 = csr[j +  6 + hi];
        int i4 = csr[j +  8 + hi], i5 = csr[j + 10 + hi];
        int i6 = csr[j + 12 + hi], i7 = csr[j + 14 + hi];
        u32x4 v0 = *(const u32x4*)(xb + (size_t)i0 * D + boff);
        u32x4 v1 = *(const u32x4*)(xb + (size_t)i1 * D + boff);
        u32x4 v2 = *(const u32x4*)(xb + (size_t)i2 * D + boff);
        u32x4 v3 = *(const u32x4*)(xb + (size_t)i3 * D + boff);
        u32x4 v4 = *(const u32x4*)(xb + (size_t)i4 * D + boff);
        u32x4 v5 = *(const u32x4*)(xb + (size_t)i5 * D + boff);
        u32x4 v6 = *(const u32x4*)(xb + (size_t)i6 * D + boff);
        u32x4 v7 = *(const u32x4*)(xb + (size_t)i7 * D + boff);
        ACC8(v0); ACC8(v1); ACC8(v2); ACC8(v3);
        ACC8(v4); ACC8(v5); ACC8(v6); ACC8(v7);
    }
    if (j + 8 <= end) {                   // one 8-edge step
        int i0 = csr[j + hi],     i1 = csr[j + 2 + hi];
        int i2 = csr[j + 4 + hi], i3 = csr[j + 6 + hi];
        u32x4 v0 = *(const u32x4*)(xb + (size_t)i0 * D + boff);
        u32x4 v1 = *(const u32x4*)(xb + (size_t)i1 * D + boff);
        u32x4 v2 = *(const u32x4*)(xb + (size_t)i2 * D + boff);
        u32x4 v3 = *(const u32x4*)(xb + (size_t)i3 * D + boff);
        ACC8(v0); ACC8(v1); ACC8(v2); ACC8(v3);
        j += 8;
    }
    if (j < end) {                        // masked final: 0..7 edges, branchless
        int lim = end - 1;
        int e0 = j + hi, e1 = j + 2 + hi, e2 = j + 4 + hi, e3 = j + 6 + hi;
        int s0 = csr[min(e0, lim)], s1 = csr[min(e1, lim)];
        int s2 = csr[min(e2, lim)], s3 = csr[min(e3, lim)];
        u32x4 v0 = *(const u32x4*)(xb + (size_t)s0 * D + boff);
        u32x4 v1 = *(const u32x4*)(xb + (size_t)s1 * D + boff);
        u32x4 v2 = *(const u32x4*)(xb + (size_t)s2 * D + boff);
        u32x4 v3 = *(const u32x4*)(xb + (size_t)s3 * D + boff);
        unsigned int m0 = (e0 < end) ? 0xFFFFFFFFu : 0u;
        unsigned int m1 = (e1 < end) ? 0xFFFFFFFFu : 0u;
        unsigned int m2 = (e2 < end) ? 0xFFFFFFFFu : 0u;
        unsigned int m3 = (e3 < end) ? 0xFFFFFFFFu : 0u;
        #pragma unroll
        for (int e = 0; e < 4; ++e) { v0[e] &= m0; v1[e] &= m1; v2[e] &= m2; v3[e] &= m3; }
        ACC8(v0); ACC8(v1); ACC8(v2); ACC8(v3);
    }
    #undef ACC8

    // combine the two 16-lane halves (same column set, disjoint edge subsets)
    #pragma unroll
    for (int e = 0; e < 4; ++e) {
        acc[e].x += __shfl_xor(acc[e].x, 16);
        acc[e].y += __shfl_xor(acc[e].y, 16);
    }

    if (hi == 0) {                        // 16 lanes x 16 B = full row
        u32x4 o;
        #pragma unroll
        for (int e = 0; e < 4; ++e) {
            unsigned int lo = f2bf(acc[e].x);
            unsigned int hf = f2bf(acc[e].y);
            o[e] = lo | (hf << 16);
        }
        __builtin_nontemporal_store(o, (u32x4*)(ub + (size_t)node * D + boff));
    }
}

// ---------------------------------------------------------------------------
// Fused 2-layer MLP (bf16 MFMA), round-8 verified.
// ---------------------------------------------------------------------------
__global__ __launch_bounds__(256, 2) void mlp_fused(
    const unsigned short* __restrict__ in,
    const unsigned short* __restrict__ W1t, const float* __restrict__ b1,
    const unsigned short* __restrict__ W2t, const float* __restrict__ b2,
    float* __restrict__ out, int N)
{
    __shared__ unsigned short Wl[128 * LDSPITCH];  // 34816 B
    __shared__ unsigned short Al[64 * LDSPITCH];   // 17408 B

    int tid = threadIdx.x;
    int row0 = blockIdx.x * 64;
    int wave = tid >> 6, lane = tid & 63;
    int l16 = lane & 15, lq = lane >> 4;

    for (int i = tid; i < 128 * 16; i += 256) {
        int r = i >> 4, cc = i & 15;
        ((int4*)(Wl + r * LDSPITCH))[cc] = ((const int4*)(W1t + r * 128))[cc];
    }
    for (int i = tid; i < 64 * 16; i += 256) {
        int r = i >> 4, cc = i & 15;
        int4 v = make_int4(0, 0, 0, 0);
        if (row0 + r < N) v = ((const int4*)(in + (size_t)(row0 + r) * 128))[cc];
        ((int4*)(Al + r * LDSPITCH))[cc] = v;
    }
    __syncthreads();

    f32x4 acc[8];
    #pragma unroll
    for (int t = 0; t < 8; ++t) acc[t] = (f32x4){0.f, 0.f, 0.f, 0.f};

    int arow = wave * 16 + l16;
    #pragma unroll
    for (int kk = 0; kk < 4; ++kk) {
        int k0 = kk * 32 + lq * 8;
        bf16x8 a = *(const bf16x8*)(Al + arow * LDSPITCH + k0);
        #pragma unroll
        for (int t = 0; t < 8; ++t) {
            bf16x8 b = *(const bf16x8*)(Wl + (t * 16 + l16) * LDSPITCH + k0);
            acc[t] = __builtin_amdgcn_mfma_f32_16x16x32_bf16(a, b, acc[t], 0, 0, 0);
        }
    }
    __syncthreads();

    for (int i = tid; i < 128 * 16; i += 256) {
        int r = i >> 4, cc = i & 15;
        ((int4*)(Wl + r * LDSPITCH))[cc] = ((const int4*)(W2t + r * 128))[cc];
    }
    #pragma unroll
    for (int t = 0; t < 8; ++t) {
        int col = t * 16 + l16;
        float bv = b1[col];
        #pragma unroll
        for (int r = 0; r < 4; ++r) {
            int row = wave * 16 + lq * 4 + r;
            float v = fmaxf(acc[t][r] + bv, 0.0f);
            Al[row * LDSPITCH + col] = f2bf(v);
        }
    }
    __syncthreads();

    #pragma unroll
    for (int t = 0; t < 8; ++t) acc[t] = (f32x4){0.f, 0.f, 0.f, 0.f};
    #pragma unroll
    for (int kk = 0; kk < 4; ++kk) {
        int k0 = kk * 32 + lq * 8;
        bf16x8 a = *(const bf16x8*)(Al + arow * LDSPITCH + k0);
        #pragma unroll
        for (int t = 0; t < 8; ++t) {
            bf16x8 b = *(const bf16x8*)(Wl + (t * 16 + l16) * LDSPITCH + k0);
            acc[t] = __builtin_amdgcn_mfma_f32_16x16x32_bf16(a, b, acc[t], 0, 0, 0);
        }
    }

    #pragma unroll
    for (int t = 0; t < 8; ++t) {
        int col = t * 16 + l16;
        float bv = b2[col];
        #pragma unroll
        for (int r = 0; r < 4; ++r) {
            int row = row0 + wave * 16 + lq * 4 + r;
            if (row >= N) continue;
            out[(size_t)row * 128 + col] = acc[t][r] + bv;
        }
    }
}

extern "C" void kernel_launch(void* const* d_in, const int* in_sizes, int n_in,
                              void* d_out, int out_size, void* d_ws, size_t ws_size,
                              hipStream_t stream) {
    const float* x   = (const float*)d_in[0];
    const int*   ei  = (const int*)d_in[1];    // edge_index [2][E]
    const float* eps = (const float*)d_in[2];
    const float* W1  = (const float*)d_in[3];
    const float* b1  = (const float*)d_in[4];
    const float* W2  = (const float*)d_in[5];
    const float* b2  = (const float*)d_in[6];
    float* out = (float*)d_out;

    int E = in_sizes[1] / 2;                   // 1,600,000
    int N = in_sizes[0] / D;                   // 100,000
    int nbuck = (N + 127) >> BSHIFT;           // 782
    int ncur = nbuck * NSUB;                   // 6256

    // workspace layout (bytes):
    //   [0, 28672)               cur   int[nbuck*8]   (25,024 used)
    //   [28672, 32768)           (free — was bbase)
    //   [32768, 432768)          rs    int[N]
    //   [434176, 10043392)       pairs int[nbuck*8*SUBCAP]  (9.6 MB)
    //   [10044416, 16444416)     csr   int[E]
    //   [16445440, 42045440)     xb    bf16[N*D]
    //   [42046464, 67646464)     ub    bf16[N*D]
    //   [67647488, +32768)       W1t   bf16[128*128]
    //   [67680256, +32768)       W2t   bf16[128*128]
    char* ws = (char*)d_ws;
    int* cur   = (int*)(ws);
    int* rs    = (int*)(ws + 32768);
    int* pairs = (int*)(ws + 434176);
    int* csr   = (int*)(ws + 10044416);
    unsigned short* xb  = (unsigned short*)(ws + 16445440);
    unsigned short* ub  = (unsigned short*)(ws + 42046464);
    unsigned short* W1t = (unsigned short*)(ws + 67647488);
    unsigned short* W2t = (unsigned short*)(ws + 67680256);

    int total4 = N * D / 4;                    // 3,200,000
    int convtot = total4 + 32768 + ncur;
    conv_all<<<(convtot + 255) / 256, 256, 0, stream>>>(
        x, xb, W1, W1t, W2, W2t, cur, total4, ncur);

    bin_kernel<<<256, 512, 0, stream>>>(ei, cur, pairs, E, nbuck);
    local_fill<<<nbuck, 256, 0, stream>>>(cur, pairs, csr, rs, N);

    gather_kernel<<<(N + 7) / 8, 256, 0, stream>>>(xb, eps, rs, csr, ub, N);

    int gemm_blocks = (N + 63) / 64;           // 1563
    mlp_fused<<<gemm_blocks, 256, 0, stream>>>(ub, W1t, b1, W2t, b2, out, N);
}